// Round 4
// baseline (692.408 us; speedup 1.0000x reference)
//
#include <hip/hip_runtime.h>
#include <hip/hip_bf16.h>
#include <stdint.h>

typedef __attribute__((ext_vector_type(4))) float f32x4;
typedef __attribute__((ext_vector_type(8))) short bf16x8;
typedef __attribute__((ext_vector_type(8))) unsigned short u16x8;

#define N_GENE 16384
#define N_TF   512
#define DMODEL 512
#define L2E    1.44269504088896340736f

__device__ __forceinline__ float bf2f(unsigned short u) {
    union { unsigned int i; float f; } v; v.i = ((unsigned int)u) << 16; return v.f;
}
// single-instruction RNE f32->bf16
__device__ __forceinline__ unsigned short f2bf(float f) {
    unsigned int r;
    asm("v_cvt_pk_bf16_f32 %0, %1, %1" : "=v"(r) : "v"(f));
    return (unsigned short)r;
}
__device__ __forceinline__ float fast_rcp(float x) {
    float r; asm("v_rcp_f32 %0, %1" : "=v"(r) : "v"(x)); return r;
}
__device__ __forceinline__ float fast_exp2(float x) {
    float r; asm("v_exp_f32 %0, %1" : "=v"(r) : "v"(x)); return r;
}

#define GLOBAL_AS(p) ((const __attribute__((address_space(1))) void*)(p))
#define LDS_AS(p)    ((__attribute__((address_space(3))) void*)(p))

// ---------------------------------------------------------------- prep: zerof + transpose6 + cvt3 fused
__global__ __launch_bounds__(256) void prep(const float* __restrict__ z0, const float* __restrict__ z1,
                                            const float* __restrict__ z2, unsigned short* __restrict__ zb,
                                            const float* __restrict__ w0, const float* __restrict__ w1,
                                            const float* __restrict__ w2, const float* __restrict__ w3,
                                            const float* __restrict__ w4, const float* __restrict__ w5,
                                            unsigned short* __restrict__ wt, float* __restrict__ lp) {
    __shared__ unsigned short tile[32][33];
    const int b = blockIdx.x;
    const int tid = threadIdx.x;
    if (b < 12288) {
        const float* s = b < 4096 ? z0 : (b < 8192 ? z1 : z2);
        const int m = b >> 12;
        const int blk = b & 4095;
        size_t i = ((size_t)blk * 256 + tid) * 8;
        float4 a = *(const float4*)(s + i);
        float4 c = *(const float4*)(s + i + 4);
        unsigned int q0, q1, q2, q3;
        asm("v_cvt_pk_bf16_f32 %0, %1, %2" : "=v"(q0) : "v"(a.x), "v"(a.y));
        asm("v_cvt_pk_bf16_f32 %0, %1, %2" : "=v"(q1) : "v"(a.z), "v"(a.w));
        asm("v_cvt_pk_bf16_f32 %0, %1, %2" : "=v"(q2) : "v"(c.x), "v"(c.y));
        asm("v_cvt_pk_bf16_f32 %0, %1, %2" : "=v"(q3) : "v"(c.z), "v"(c.w));
        uint4 o; o.x = q0; o.y = q1; o.z = q2; o.w = q3;
        *(uint4*)(zb + (size_t)m * (size_t)N_GENE * 512 + i) = o;
    } else if (b < 13824) {
        const float* srcs[6] = { w0, w1, w2, w3, w4, w5 };
        const int b2 = b - 12288;
        const int m = b2 >> 8;
        const int rem = b2 & 255;
        const int by = rem >> 4, bx = rem & 15;
        const int tx = tid & 31, ty8 = tid >> 5;
        const float* src = srcs[m];
        const int x = bx * 32 + tx;
        const int y0 = by * 32;
        for (int i = ty8; i < 32; i += 8)
            tile[i][tx] = f2bf(src[(size_t)(y0 + i) * 512 + x]);
        __syncthreads();
        const int xo = by * 32 + tx;
        const int yo0 = bx * 32;
        unsigned short* d = wt + (size_t)m * 512 * 512;
        for (int i = ty8; i < 32; i += 8)
            d[(size_t)(yo0 + i) * 512 + xo] = tile[tx][i];
    } else {
        for (int i = tid; i < 8 * N_TF; i += 256) lp[i] = 0.f;
    }
}

// ---------------------------------------------------------------- GEMM C[M,512] = A[M,512] @ Bt^T
// All 6 projections in one dispatch: grid (4, 132, 3); y<128 -> K-proj tile, y>=128 -> Q-proj (gathered).
__global__ __launch_bounds__(256) void gemm_all(const unsigned short* __restrict__ Zb,
                                                const unsigned short* __restrict__ Wt,
                                                unsigned short* __restrict__ Kp,
                                                unsigned short* __restrict__ Qp,
                                                const int* __restrict__ tf_idx) {
    __shared__ unsigned short As[128 * 64];   // 16 KB
    __shared__ unsigned short Bs[128 * 64];   // 16 KB
    const int e = blockIdx.z;
    const unsigned short* A = Zb + (size_t)e * N_GENE * 512;
    const unsigned short* Bt;
    unsigned short* C;
    const int* idx;
    int mBase;
    if (blockIdx.y < 128) {
        Bt = Wt + (size_t)(e * 2 + 1) * 262144;
        C = Kp + (size_t)e * N_GENE * 512;
        idx = nullptr;
        mBase = blockIdx.y * 128;
    } else {
        Bt = Wt + (size_t)(e * 2) * 262144;
        C = Qp + (size_t)e * 512 * 512;
        idx = tf_idx;
        mBase = (blockIdx.y - 128) * 128;
    }
    const int tid = threadIdx.x;
    const int lane = tid & 63;
    const int w = tid >> 6;
    const int nBase = blockIdx.x * 128;
    const int wm = (w & 1) * 64;
    const int wn = (w >> 1) * 64;
    const int lm = lane & 15, lq = lane >> 4;

    const int rbase = tid >> 3;                       // 0..31
    const int seg = tid & 7;
    const int scol = ((seg ^ (rbase & 7)) << 3);      // pre-swizzled source col (elements)
    const unsigned short* aSrc[4];
    const unsigned short* bSrc[4];
    #pragma unroll
    for (int i = 0; i < 4; ++i) {
        int r = i * 32 + rbase;
        int ar = idx ? idx[mBase + r] : (mBase + r);
        aSrc[i] = A + (size_t)ar * 512 + scol;
        bSrc[i] = Bt + (size_t)(nBase + r) * 512 + scol;
    }
    const int ldsOfs = (tid & 192) * 8;               // wave-uniform elem base

    f32x4 acc[4][4] = {};

    for (int k0 = 0; k0 < 512; k0 += 64) {
        #pragma unroll
        for (int i = 0; i < 4; ++i) {
            __builtin_amdgcn_global_load_lds(GLOBAL_AS(aSrc[i] + k0), LDS_AS(As + i * 2048 + ldsOfs), 16, 0, 0);
            __builtin_amdgcn_global_load_lds(GLOBAL_AS(bSrc[i] + k0), LDS_AS(Bs + i * 2048 + ldsOfs), 16, 0, 0);
        }
        __syncthreads();
        bf16x8 af[4][2], bfr[4][2];
        #pragma unroll
        for (int mt = 0; mt < 4; ++mt) {
            int row = wm + mt * 16 + lm;
            int sw = row & 7;
            #pragma unroll
            for (int hh = 0; hh < 2; ++hh)
                af[mt][hh] = *(const bf16x8*)(As + row * 64 + (((hh * 4 + lq) ^ sw) << 3));
        }
        #pragma unroll
        for (int nt = 0; nt < 4; ++nt) {
            int row = wn + nt * 16 + lm;
            int sw = row & 7;
            #pragma unroll
            for (int hh = 0; hh < 2; ++hh)
                bfr[nt][hh] = *(const bf16x8*)(Bs + row * 64 + (((hh * 4 + lq) ^ sw) << 3));
        }
        #pragma unroll
        for (int mt = 0; mt < 4; ++mt)
            #pragma unroll
            for (int nt = 0; nt < 4; ++nt) {
                acc[mt][nt] = __builtin_amdgcn_mfma_f32_16x16x32_bf16(af[mt][0], bfr[nt][0], acc[mt][nt], 0, 0, 0);
                acc[mt][nt] = __builtin_amdgcn_mfma_f32_16x16x32_bf16(af[mt][1], bfr[nt][1], acc[mt][nt], 0, 0, 0);
            }
        __syncthreads();
    }
    #pragma unroll
    for (int mt = 0; mt < 4; ++mt)
        #pragma unroll
        for (int nt = 0; nt < 4; ++nt)
            #pragma unroll
            for (int r = 0; r < 4; ++r) {
                int m = mBase + wm + mt * 16 + lq * 4 + r;
                int n = nBase + wn + nt * 16 + lm;
                C[(size_t)m * 512 + n] = f2bf(acc[mt][nt][r]);
            }
}

// ---------------------------------------------------------------- fused score+gate+softmax pass
// Block: 64 t x 64 g. 4 waves; wave w owns t [tw,+32), g [g0,+32). XCD-chunked swizzle, ty-innermost.
// Write path: P tile staged per-wave in LDS (scatter b16 writes, padded stride), then contiguous
// b128 nontemporal stores (full sectors, 16x fewer store insts). alpha_mean uses NORMAL stores so
// the 3 interleaved dword streams merge in L2 and write back as full lines (nt bypassed merging ->
// 3x burst inflation seen in round-3 counters). u_mean stays nt (64B-contiguous per inst).
__global__ __launch_bounds__(256, 4) void score_pass(const unsigned short* __restrict__ Qp,   // [3][512][512] bf16
                                                     const unsigned short* __restrict__ Kp,   // [3][16384][512] bf16
                                                     const float* __restrict__ gw,            // [8][3][3]
                                                     const float* __restrict__ gb,            // [8][3]
                                                     unsigned short* __restrict__ p_out,      // [8][512][16384] bf16
                                                     float* __restrict__ l_out,               // [8][512]
                                                     float* __restrict__ u_mean,              // [512][16384]
                                                     float* __restrict__ alpha_mean)          // [512][16384][3]
{
    __shared__ unsigned short pbuf[4][32 * 40];   // per-wave 32t x 32g tile, row stride 40 shorts (80B)
    const int tid = threadIdx.x;
    const int lane = tid & 63;
    const int w = tid >> 6;
    const int bid = blockIdx.x;                 // grid = 2048 (1-D)
    const int o = (bid & 7) * 256 + (bid >> 3);
    const int gx = o >> 3;                      // 0..255 : 64-gene chunk
    const int ty = o & 7;                       // 0..7   : 64-tf chunk (innermost -> K reuse in L2)
    const int tw = ty * 64 + (w & 1) * 32;
    const int g0 = gx * 64 + (w >> 1) * 32;
    const int lm = lane & 15, lq = lane >> 4;
    unsigned short* pw = &pbuf[w][0];

    float u_sum[2][2][4] = {};      // [mt][nt][r]
    float a0_sum[2][2][4] = {};
    float a1_sum[2][2][4] = {};

    #pragma unroll 1
    for (int h = 0; h < 8; ++h) {
        // gate weights folded with score scale (1/8) and log2(e) for native v_exp_f32
        float W2[3][3], B2[3];
        #pragma unroll
        for (int e = 0; e < 3; ++e)
            #pragma unroll
            for (int f = 0; f < 3; ++f) W2[e][f] = gw[(h * 3 + e) * 3 + f] * (0.125f * L2E);
        #pragma unroll
        for (int f = 0; f < 3; ++f) B2[f] = gb[h * 3 + f] * L2E;

        f32x4 s[3][2][2];
        #pragma unroll
        for (int e = 0; e < 3; ++e) {
            const unsigned short* qbase = Qp + (size_t)e * 512 * 512 + (size_t)(tw + lm) * 512 + h * 64 + lq * 8;
            const unsigned short* kbase = Kp + (size_t)e * N_GENE * 512 + (size_t)(g0 + lm) * 512 + h * 64 + lq * 8;
            bf16x8 q[2][2], k[2][2];
            #pragma unroll
            for (int mt = 0; mt < 2; ++mt) {
                q[mt][0] = *(const bf16x8*)(qbase + mt * 16 * 512);
                q[mt][1] = *(const bf16x8*)(qbase + mt * 16 * 512 + 32);
            }
            #pragma unroll
            for (int nt = 0; nt < 2; ++nt) {
                k[nt][0] = *(const bf16x8*)(kbase + nt * 16 * 512);
                k[nt][1] = *(const bf16x8*)(kbase + nt * 16 * 512 + 32);
            }
            #pragma unroll
            for (int mt = 0; mt < 2; ++mt)
                #pragma unroll
                for (int nt = 0; nt < 2; ++nt) {
                    f32x4 a = {};
                    a = __builtin_amdgcn_mfma_f32_16x16x32_bf16(q[mt][0], k[nt][0], a, 0, 0, 0);
                    a = __builtin_amdgcn_mfma_f32_16x16x32_bf16(q[mt][1], k[nt][1], a, 0, 0, 0);
                    s[e][mt][nt] = a;
                }
        }
        float lpart[2][4] = {};
        #pragma unroll
        for (int mt = 0; mt < 2; ++mt)
            #pragma unroll
            for (int nt = 0; nt < 2; ++nt) {
                #pragma unroll
                for (int r = 0; r < 4; ++r) {
                    float s0 = s[0][mt][nt][r];
                    float s1 = s[1][mt][nt][r];
                    float s2 = s[2][mt][nt][r];
                    float gl0 = fmaf(s2, W2[2][0], fmaf(s1, W2[1][0], fmaf(s0, W2[0][0], B2[0])));
                    float gl1 = fmaf(s2, W2[2][1], fmaf(s1, W2[1][1], fmaf(s0, W2[0][1], B2[1])));
                    float gl2 = fmaf(s2, W2[2][2], fmaf(s1, W2[1][2], fmaf(s0, W2[0][2], B2[2])));
                    float e0 = fast_exp2(gl0), e1 = fast_exp2(gl1), e2 = fast_exp2(gl2);
                    float rz = fast_rcp(e0 + e1 + e2);
                    float a0 = e0 * rz, a1 = e1 * rz;
                    float dot = fmaf(e0, s0, fmaf(e1, s1, e2 * s2));
                    float u = dot * (rz * 0.125f);           // = sum_e alpha_e * (s_e/8)
                    float pv = fast_exp2(u * L2E);           // exp(u); |u| small -> fp32-safe
                    u_sum[mt][nt][r] += u;
                    a0_sum[mt][nt][r] += a0;
                    a1_sum[mt][nt][r] += a1;
                    lpart[mt][r] += pv;
                    pw[(mt * 16 + lq * 4 + r) * 40 + nt * 16 + lm] = f2bf(pv);
                }
            }
        // drain wave-private LDS tile -> contiguous nt b128 stores (2 per thread per h)
        {
            const int rrow = lane >> 1, half = lane & 1;
            const unsigned short* src = pw + rrow * 40 + half * 16;
            bf16x8 v0 = *(const bf16x8*)(src);
            bf16x8 v1 = *(const bf16x8*)(src + 8);
            unsigned short* pg = p_out + ((size_t)h * N_TF + (tw + rrow)) * (size_t)N_GENE + (g0 + half * 16);
            __builtin_nontemporal_store(v0, (bf16x8*)pg);
            __builtin_nontemporal_store(v1, (bf16x8*)(pg + 8));
        }
        #pragma unroll
        for (int mt = 0; mt < 2; ++mt)
            #pragma unroll
            for (int r = 0; r < 4; ++r) {
                float v = lpart[mt][r];
                v += __shfl_xor(v, 1);
                v += __shfl_xor(v, 2);
                v += __shfl_xor(v, 4);
                v += __shfl_xor(v, 8);
                if (lm == 0) atomicAdd(&l_out[h * N_TF + tw + mt * 16 + lq * 4 + r], v);
            }
    }
    #pragma unroll
    for (int mt = 0; mt < 2; ++mt)
        #pragma unroll
        for (int nt = 0; nt < 2; ++nt)
            #pragma unroll
            for (int r = 0; r < 4; ++r) {
                int t = tw + mt * 16 + lq * 4 + r;
                int g = g0 + nt * 16 + lm;
                __builtin_nontemporal_store(u_sum[mt][nt][r] * 0.125f, u_mean + (size_t)t * N_GENE + g);
                float a0m = a0_sum[mt][nt][r] * 0.125f;
                float a1m = a1_sum[mt][nt][r] * 0.125f;
                size_t base = ((size_t)t * N_GENE + g) * 3;
                alpha_mean[base + 0] = a0m;                  // normal stores: L2 merges the 3 streams
                alpha_mean[base + 1] = a1m;
                alpha_mean[base + 2] = 1.0f - a0m - a1m;
            }
}

// ---------------------------------------------------------------- A_mean finalize (fp32 out)
__global__ __launch_bounds__(256) void finalize_A(const unsigned short* __restrict__ p,
                                                  const float* __restrict__ l,
                                                  float* __restrict__ A_mean) {
    const int t = blockIdx.x;
    float rinv[8];
    #pragma unroll
    for (int h = 0; h < 8; ++h) rinv[h] = 0.125f / l[h * N_TF + t];
    const int gbase = blockIdx.y * 4096 + threadIdx.x * 8;
    #pragma unroll
    for (int gg = 0; gg < 2; ++gg) {
        int g8 = gbase + gg * 2048;
        float s[8] = {};
        #pragma unroll
        for (int h = 0; h < 8; ++h) {
            u16x8 pv = __builtin_nontemporal_load((const u16x8*)(p + ((size_t)h * N_TF + t) * N_GENE + g8));
            float r = rinv[h];
            #pragma unroll
            for (int j = 0; j < 8; ++j) s[j] += bf2f(pv[j]) * r;
        }
        f32x4 o0, o1;
        o0[0] = s[0]; o0[1] = s[1]; o0[2] = s[2]; o0[3] = s[3];
        o1[0] = s[4]; o1[1] = s[5]; o1[2] = s[6]; o1[3] = s[7];
        __builtin_nontemporal_store(o0, (f32x4*)(A_mean + (size_t)t * N_GENE + g8));
        __builtin_nontemporal_store(o1, (f32x4*)(A_mean + (size_t)t * N_GENE + g8 + 4));
    }
}

// ---------------------------------------------------------------- H_TF + H_G passthrough in one launch
__global__ __launch_bounds__(256) void copy_all(const int4* __restrict__ a, const int4* __restrict__ b,
                                                int4* __restrict__ da, int4* __restrict__ db) {
    const int bx = blockIdx.x;
    if (bx < 256) {
        int i = bx * 256 + threadIdx.x;            // 65536 int4 = 1 MB H_TF
        da[i] = a[i];
    } else {
        int i = (bx - 256) * 256 + threadIdx.x;    // 2097152 int4 = 32 MB H_G
        db[i] = b[i];
    }
}

// ---------------------------------------------------------------- launch
extern "C" void kernel_launch(void* const* d_in, const int* in_sizes, int n_in,
                              void* d_out, int out_size, void* d_ws, size_t ws_size,
                              hipStream_t stream) {
    const float* H_TF  = (const float*)d_in[0];
    const float* H_G   = (const float*)d_in[1];
    // evidence order: e0=bind(seq), e1=coexpr(exp), e2=know(txt)
    const float* z[3]  = { (const float*)d_in[3], (const float*)d_in[2], (const float*)d_in[4] };
    const int* tf_idx  = (const int*)d_in[5];
    const float* Wq[3] = { (const float*)d_in[6], (const float*)d_in[8], (const float*)d_in[10] };
    const float* Wk[3] = { (const float*)d_in[7], (const float*)d_in[9], (const float*)d_in[11] };
    const float* gw    = (const float*)d_in[12];
    const float* gb    = (const float*)d_in[13];
    float* out = (float*)d_out;

    // d_out layout (fp32): H_TF | H_G | A_mean | u_mean | alpha_mean
    float* out_HTF   = out;
    float* out_HG    = out + 262144;
    float* out_Amean = out + 262144 + 8388608;
    float* out_umean = out + 262144 + 8388608 + 8388608;
    float* out_alpha = out + 262144 + 8388608 + 8388608 + 8388608;

    // ws layout (bf16 intermediates)
    unsigned short* Wt = (unsigned short*)d_ws;        // 6 * 262144  (slot e*2 = Wq_e^T, e*2+1 = Wk_e^T)
    unsigned short* Kp = Wt + 6 * 262144;              // 3 * 16384*512
    unsigned short* Qp = Kp + 3 * (size_t)N_GENE * 512;// 3 * 512*512
    unsigned short* Pp = Qp + 3 * 512 * 512;           // 8 * 512 * 16384
    float*          Lp = (float*)(Pp + (size_t)8 * N_TF * N_GENE);  // 8*512 floats
    // Zb (bf16 copies of z) aliases Pp: Zb is dead before score_pass writes Pp
    unsigned short* Zb = Pp;                           // 3 * 16384*512 <= Pp size

    // 1) all preprocessing in one dispatch
    prep<<<13825, 256, 0, stream>>>(z[0], z[1], z[2], Zb,
                                    Wq[0], Wk[0], Wq[1], Wk[1], Wq[2], Wk[2], Wt, Lp);

    // 2) all 6 projection GEMMs in one dispatch
    gemm_all<<<dim3(4, 132, 3), 256, 0, stream>>>(Zb, Wt, Kp, Qp, tf_idx);

    // 3) fused score+gate+softmax
    score_pass<<<2048, 256, 0, stream>>>(Qp, Kp, gw, gb, Pp, Lp, out_umean, out_alpha);

    // 4) A_mean normalize+mean
    finalize_A<<<dim3(512, 4), 256, 0, stream>>>(Pp, Lp, out_Amean);

    // 5) passthrough copies
    copy_all<<<256 + 8192, 256, 0, stream>>>((const int4*)H_TF, (const int4*)H_G,
                                             (int4*)out_HTF, (int4*)out_HG);
}

// Round 6
// 641.683 us; speedup vs baseline: 1.0791x; 1.0791x over previous
//
#include <hip/hip_runtime.h>
#include <hip/hip_bf16.h>
#include <stdint.h>

typedef __attribute__((ext_vector_type(4))) float f32x4;
typedef __attribute__((ext_vector_type(8))) short bf16x8;
typedef __attribute__((ext_vector_type(8))) unsigned short u16x8;

#define N_GENE 16384
#define N_TF   512
#define DMODEL 512
#define L2E    1.44269504088896340736f

__device__ __forceinline__ float bf2f(unsigned short u) {
    union { unsigned int i; float f; } v; v.i = ((unsigned int)u) << 16; return v.f;
}
// single-instruction RNE f32->bf16
__device__ __forceinline__ unsigned short f2bf(float f) {
    unsigned int r;
    asm("v_cvt_pk_bf16_f32 %0, %1, %1" : "=v"(r) : "v"(f));
    return (unsigned short)r;
}
__device__ __forceinline__ float fast_rcp(float x) {
    float r; asm("v_rcp_f32 %0, %1" : "=v"(r) : "v"(x)); return r;
}
__device__ __forceinline__ float fast_exp2(float x) {
    float r; asm("v_exp_f32 %0, %1" : "=v"(r) : "v"(x)); return r;
}

#define GLOBAL_AS(p) ((const __attribute__((address_space(1))) void*)(p))
#define LDS_AS(p)    ((__attribute__((address_space(3))) void*)(p))

// ---------------------------------------------------------------- prep: zerof + transpose6 + cvt3 fused
__global__ __launch_bounds__(256) void prep(const float* __restrict__ z0, const float* __restrict__ z1,
                                            const float* __restrict__ z2, unsigned short* __restrict__ zb,
                                            const float* __restrict__ w0, const float* __restrict__ w1,
                                            const float* __restrict__ w2, const float* __restrict__ w3,
                                            const float* __restrict__ w4, const float* __restrict__ w5,
                                            unsigned short* __restrict__ wt, float* __restrict__ lp) {
    __shared__ unsigned short tile[32][33];
    const int b = blockIdx.x;
    const int tid = threadIdx.x;
    if (b < 12288) {
        const float* s = b < 4096 ? z0 : (b < 8192 ? z1 : z2);
        const int m = b >> 12;
        const int blk = b & 4095;
        size_t i = ((size_t)blk * 256 + tid) * 8;
        float4 a = *(const float4*)(s + i);
        float4 c = *(const float4*)(s + i + 4);
        unsigned int q0, q1, q2, q3;
        asm("v_cvt_pk_bf16_f32 %0, %1, %2" : "=v"(q0) : "v"(a.x), "v"(a.y));
        asm("v_cvt_pk_bf16_f32 %0, %1, %2" : "=v"(q1) : "v"(a.z), "v"(a.w));
        asm("v_cvt_pk_bf16_f32 %0, %1, %2" : "=v"(q2) : "v"(c.x), "v"(c.y));
        asm("v_cvt_pk_bf16_f32 %0, %1, %2" : "=v"(q3) : "v"(c.z), "v"(c.w));
        uint4 o; o.x = q0; o.y = q1; o.z = q2; o.w = q3;
        *(uint4*)(zb + (size_t)m * (size_t)N_GENE * 512 + i) = o;
    } else if (b < 13824) {
        const float* srcs[6] = { w0, w1, w2, w3, w4, w5 };
        const int b2 = b - 12288;
        const int m = b2 >> 8;
        const int rem = b2 & 255;
        const int by = rem >> 4, bx = rem & 15;
        const int tx = tid & 31, ty8 = tid >> 5;
        const float* src = srcs[m];
        const int x = bx * 32 + tx;
        const int y0 = by * 32;
        for (int i = ty8; i < 32; i += 8)
            tile[i][tx] = f2bf(src[(size_t)(y0 + i) * 512 + x]);
        __syncthreads();
        const int xo = by * 32 + tx;
        const int yo0 = bx * 32;
        unsigned short* d = wt + (size_t)m * 512 * 512;
        for (int i = ty8; i < 32; i += 8)
            d[(size_t)(yo0 + i) * 512 + xo] = tile[tx][i];
    } else {
        for (int i = tid; i < 8 * N_TF; i += 256) lp[i] = 0.f;
    }
}

// ---------------------------------------------------------------- GEMM C[M,512] = A[M,512] @ Bt^T
__global__ __launch_bounds__(256) void gemm_all(const unsigned short* __restrict__ Zb,
                                                const unsigned short* __restrict__ Wt,
                                                unsigned short* __restrict__ Kp,
                                                unsigned short* __restrict__ Qp,
                                                const int* __restrict__ tf_idx) {
    __shared__ unsigned short As[128 * 64];   // 16 KB
    __shared__ unsigned short Bs[128 * 64];   // 16 KB
    const int e = blockIdx.z;
    const unsigned short* A = Zb + (size_t)e * N_GENE * 512;
    const unsigned short* Bt;
    unsigned short* C;
    const int* idx;
    int mBase;
    if (blockIdx.y < 128) {
        Bt = Wt + (size_t)(e * 2 + 1) * 262144;
        C = Kp + (size_t)e * N_GENE * 512;
        idx = nullptr;
        mBase = blockIdx.y * 128;
    } else {
        Bt = Wt + (size_t)(e * 2) * 262144;
        C = Qp + (size_t)e * 512 * 512;
        idx = tf_idx;
        mBase = (blockIdx.y - 128) * 128;
    }
    const int tid = threadIdx.x;
    const int lane = tid & 63;
    const int w = tid >> 6;
    const int nBase = blockIdx.x * 128;
    const int wm = (w & 1) * 64;
    const int wn = (w >> 1) * 64;
    const int lm = lane & 15, lq = lane >> 4;

    const int rbase = tid >> 3;                       // 0..31
    const int seg = tid & 7;
    const int scol = ((seg ^ (rbase & 7)) << 3);      // pre-swizzled source col (elements)
    const unsigned short* aSrc[4];
    const unsigned short* bSrc[4];
    #pragma unroll
    for (int i = 0; i < 4; ++i) {
        int r = i * 32 + rbase;
        int ar = idx ? idx[mBase + r] : (mBase + r);
        aSrc[i] = A + (size_t)ar * 512 + scol;
        bSrc[i] = Bt + (size_t)(nBase + r) * 512 + scol;
    }
    const int ldsOfs = (tid & 192) * 8;               // wave-uniform elem base

    f32x4 acc[4][4] = {};

    for (int k0 = 0; k0 < 512; k0 += 64) {
        #pragma unroll
        for (int i = 0; i < 4; ++i) {
            __builtin_amdgcn_global_load_lds(GLOBAL_AS(aSrc[i] + k0), LDS_AS(As + i * 2048 + ldsOfs), 16, 0, 0);
            __builtin_amdgcn_global_load_lds(GLOBAL_AS(bSrc[i] + k0), LDS_AS(Bs + i * 2048 + ldsOfs), 16, 0, 0);
        }
        __syncthreads();
        bf16x8 af[4][2], bfr[4][2];
        #pragma unroll
        for (int mt = 0; mt < 4; ++mt) {
            int row = wm + mt * 16 + lm;
            int sw = row & 7;
            #pragma unroll
            for (int hh = 0; hh < 2; ++hh)
                af[mt][hh] = *(const bf16x8*)(As + row * 64 + (((hh * 4 + lq) ^ sw) << 3));
        }
        #pragma unroll
        for (int nt = 0; nt < 4; ++nt) {
            int row = wn + nt * 16 + lm;
            int sw = row & 7;
            #pragma unroll
            for (int hh = 0; hh < 2; ++hh)
                bfr[nt][hh] = *(const bf16x8*)(Bs + row * 64 + (((hh * 4 + lq) ^ sw) << 3));
        }
        #pragma unroll
        for (int mt = 0; mt < 4; ++mt)
            #pragma unroll
            for (int nt = 0; nt < 4; ++nt) {
                acc[mt][nt] = __builtin_amdgcn_mfma_f32_16x16x32_bf16(af[mt][0], bfr[nt][0], acc[mt][nt], 0, 0, 0);
                acc[mt][nt] = __builtin_amdgcn_mfma_f32_16x16x32_bf16(af[mt][1], bfr[nt][1], acc[mt][nt], 0, 0, 0);
            }
        __syncthreads();
    }
    #pragma unroll
    for (int mt = 0; mt < 4; ++mt)
        #pragma unroll
        for (int nt = 0; nt < 4; ++nt)
            #pragma unroll
            for (int r = 0; r < 4; ++r) {
                int m = mBase + wm + mt * 16 + lq * 4 + r;
                int n = nBase + wn + nt * 16 + lm;
                C[(size_t)m * 512 + n] = f2bf(acc[mt][nt][r]);
            }
}

// ---------------------------------------------------------------- fused score+gate+softmax pass
// Block: 64t x 64g, 4 waves. XCD-chunked swizzle (ty innermost -> K L2 reuse).
// Latency fix: K fragments re-loaded for h+1 into the SAME registers right after the MFMAs
// consume them -> the 12 K gathers are in flight during the ~2500-cycle elementwise phase.
// Write path: per-wave LDS repack for BOTH p (bf16x8 nt) and alpha (f32x4 nt) -> all streaming
// stores are full-sector vector nt; no write-allocate, no partial-sector nt inflation.
// (r5 bug fixed: alpha drain now copies all 96 floats/row — 6 chunks per lane, not 1.5.)
__global__ __launch_bounds__(256) void score_pass(const unsigned short* __restrict__ Qp,   // [3][512][512] bf16
                                                  const unsigned short* __restrict__ Kp,   // [3][16384][512] bf16
                                                  const float* __restrict__ gw,            // [8][3][3]
                                                  const float* __restrict__ gb,            // [8][3]
                                                  unsigned short* __restrict__ p_out,      // [8][512][16384] bf16
                                                  float* __restrict__ l_out,               // [8][512]
                                                  float* __restrict__ u_mean,              // [512][16384]
                                                  float* __restrict__ alpha_mean)          // [512][16384][3]
{
    __shared__ float abuf[4][1600];               // 6.4 KB per wave; p-tile (32x40 shorts) aliases this
    const int tid = threadIdx.x;
    const int lane = tid & 63;
    const int w = tid >> 6;
    const int bid = blockIdx.x;                   // grid = 2048
    const int o = (bid & 7) * 256 + (bid >> 3);
    const int gx = o >> 3;                        // 0..255 : 64-gene chunk
    const int ty = o & 7;                         // 0..7   : 64-tf chunk (innermost)
    const int tw = ty * 64 + (w & 1) * 32;
    const int g0 = gx * 64 + (w >> 1) * 32;
    const int lm = lane & 15, lq = lane >> 4;
    unsigned short* pw = (unsigned short*)(&abuf[w][0]);   // 32 x 40 shorts

    float u_sum[2][2][4] = {};
    float a0_sum[2][2][4] = {};
    float a1_sum[2][2][4] = {};

    const unsigned short* qbase0 = Qp + (size_t)(tw + lm) * 512 + lq * 8;
    const unsigned short* kbase0 = Kp + (size_t)(g0 + lm) * 512 + lq * 8;

    // preload K fragments for h=0
    bf16x8 kf[3][2][2];
    #pragma unroll
    for (int e = 0; e < 3; ++e) {
        const unsigned short* kb_ = kbase0 + (size_t)e * N_GENE * 512;
        #pragma unroll
        for (int nt = 0; nt < 2; ++nt) {
            kf[e][nt][0] = *(const bf16x8*)(kb_ + nt * 16 * 512);
            kf[e][nt][1] = *(const bf16x8*)(kb_ + nt * 16 * 512 + 32);
        }
    }

    #pragma unroll 1
    for (int h = 0; h < 8; ++h) {
        float W2[3][3], B2[3];
        #pragma unroll
        for (int e = 0; e < 3; ++e)
            #pragma unroll
            for (int f = 0; f < 3; ++f) W2[e][f] = gw[(h * 3 + e) * 3 + f] * (0.125f * L2E);
        #pragma unroll
        for (int f = 0; f < 3; ++f) B2[f] = gb[h * 3 + f] * L2E;

        // QK^T for all 3 evidences (Q loads are L2-hot; K frags were prefetched last iteration)
        f32x4 s[3][2][2];
        #pragma unroll
        for (int e = 0; e < 3; ++e) {
            const unsigned short* qb_ = qbase0 + (size_t)e * 512 * 512 + h * 64;
            bf16x8 q00 = *(const bf16x8*)(qb_);
            bf16x8 q01 = *(const bf16x8*)(qb_ + 32);
            bf16x8 q10 = *(const bf16x8*)(qb_ + 16 * 512);
            bf16x8 q11 = *(const bf16x8*)(qb_ + 16 * 512 + 32);
            #pragma unroll
            for (int nt = 0; nt < 2; ++nt) {
                f32x4 a = {};
                a = __builtin_amdgcn_mfma_f32_16x16x32_bf16(q00, kf[e][nt][0], a, 0, 0, 0);
                a = __builtin_amdgcn_mfma_f32_16x16x32_bf16(q01, kf[e][nt][1], a, 0, 0, 0);
                s[e][0][nt] = a;
                f32x4 b = {};
                b = __builtin_amdgcn_mfma_f32_16x16x32_bf16(q10, kf[e][nt][0], b, 0, 0, 0);
                b = __builtin_amdgcn_mfma_f32_16x16x32_bf16(q11, kf[e][nt][1], b, 0, 0, 0);
                s[e][1][nt] = b;
            }
        }

        // kf registers now dead -> issue next-h K gathers; they complete under the elementwise below
        if (h < 7) {
            #pragma unroll
            for (int e = 0; e < 3; ++e) {
                const unsigned short* kb_ = kbase0 + (size_t)e * N_GENE * 512 + (h + 1) * 64;
                #pragma unroll
                for (int nt = 0; nt < 2; ++nt) {
                    kf[e][nt][0] = *(const bf16x8*)(kb_ + nt * 16 * 512);
                    kf[e][nt][1] = *(const bf16x8*)(kb_ + nt * 16 * 512 + 32);
                }
            }
        }

        // elementwise gate + softmax-numerator
        float lpart[2][4] = {};
        #pragma unroll
        for (int mt = 0; mt < 2; ++mt)
            #pragma unroll
            for (int nt = 0; nt < 2; ++nt)
                #pragma unroll
                for (int r = 0; r < 4; ++r) {
                    float s0 = s[0][mt][nt][r];
                    float s1 = s[1][mt][nt][r];
                    float s2 = s[2][mt][nt][r];
                    float gl0 = fmaf(s2, W2[2][0], fmaf(s1, W2[1][0], fmaf(s0, W2[0][0], B2[0])));
                    float gl1 = fmaf(s2, W2[2][1], fmaf(s1, W2[1][1], fmaf(s0, W2[0][1], B2[1])));
                    float gl2 = fmaf(s2, W2[2][2], fmaf(s1, W2[1][2], fmaf(s0, W2[0][2], B2[2])));
                    float e0 = fast_exp2(gl0), e1 = fast_exp2(gl1), e2 = fast_exp2(gl2);
                    float rz = fast_rcp(e0 + e1 + e2);
                    float a0 = e0 * rz, a1 = e1 * rz;
                    float dot = fmaf(e0, s0, fmaf(e1, s1, e2 * s2));
                    float u = dot * (rz * 0.125f);           // = sum_e alpha_e * (s_e/8)
                    float pv = fast_exp2(u * L2E);           // exp(u); |u| small -> fp32-safe
                    u_sum[mt][nt][r] += u;
                    a0_sum[mt][nt][r] += a0;
                    a1_sum[mt][nt][r] += a1;
                    lpart[mt][r] += pv;
                    pw[(mt * 16 + lq * 4 + r) * 40 + nt * 16 + lm] = f2bf(pv);
                }
        // drain wave-private p tile -> contiguous full-sector nt b128 stores
        {
            const int rrow = lane >> 1, half = lane & 1;
            const unsigned short* src = pw + rrow * 40 + half * 16;
            bf16x8 v0 = *(const bf16x8*)(src);
            bf16x8 v1 = *(const bf16x8*)(src + 8);
            unsigned short* pg = p_out + ((size_t)h * N_TF + (tw + rrow)) * (size_t)N_GENE + (g0 + half * 16);
            __builtin_nontemporal_store(v0, (bf16x8*)pg);
            __builtin_nontemporal_store(v1, (bf16x8*)(pg + 8));
        }
        #pragma unroll
        for (int mt = 0; mt < 2; ++mt)
            #pragma unroll
            for (int r = 0; r < 4; ++r) {
                float v = lpart[mt][r];
                v += __shfl_xor(v, 1);
                v += __shfl_xor(v, 2);
                v += __shfl_xor(v, 4);
                v += __shfl_xor(v, 8);
                if (lm == 0) atomicAdd(&l_out[h * N_TF + tw + mt * 16 + lq * 4 + r], v);
            }
    }

    // tail: u_mean (nt scalar, 64B-contiguous per inst) + alpha via LDS repack (full-sector nt f32x4)
    #pragma unroll
    for (int mt = 0; mt < 2; ++mt) {
        #pragma unroll
        for (int nt = 0; nt < 2; ++nt)
            #pragma unroll
            for (int r = 0; r < 4; ++r) {
                const int row = lq * 4 + r;                  // 0..15 within this t-half
                const int colg = nt * 16 + lm;               // 0..31
                __builtin_nontemporal_store(u_sum[mt][nt][r] * 0.125f,
                                            u_mean + (size_t)(tw + mt * 16 + row) * N_GENE + g0 + colg);
                float a0m = a0_sum[mt][nt][r] * 0.125f;
                float a1m = a1_sum[mt][nt][r] * 0.125f;
                float* ab = &abuf[w][row * 100 + colg * 3];
                ab[0] = a0m;
                ab[1] = a1m;
                ab[2] = 1.0f - a0m - a1m;                    // exact: per-h alphas sum to 1
            }
        // drain 16 rows x 96 floats: 4 lanes/row x 6 f32x4 each; per (j) the 4 dk-lanes cover
        // a contiguous 64B span -> all full-sector nt stores
        {
            const int drow = lane & 15;
            const int dk = lane >> 4;                        // 0..3
            const float* srcb = &abuf[w][drow * 100];
            float* dst = alpha_mean + (size_t)(tw + mt * 16 + drow) * (N_GENE * 3) + (size_t)g0 * 3;
            #pragma unroll
            for (int j = 0; j < 6; ++j) {
                const int c = (j * 4 + dk) * 4;              // float offset 0..92
                f32x4 v = *(const f32x4*)(srcb + c);
                __builtin_nontemporal_store(v, (f32x4*)(dst + c));
            }
        }
    }
}

// ---------------------------------------------------------------- A_mean finalize (fp32 out)
__global__ __launch_bounds__(256) void finalize_A(const unsigned short* __restrict__ p,
                                                  const float* __restrict__ l,
                                                  float* __restrict__ A_mean) {
    const int t = blockIdx.x;
    float rinv[8];
    #pragma unroll
    for (int h = 0; h < 8; ++h) rinv[h] = 0.125f / l[h * N_TF + t];
    const int gbase = blockIdx.y * 4096 + threadIdx.x * 8;
    #pragma unroll
    for (int gg = 0; gg < 2; ++gg) {
        int g8 = gbase + gg * 2048;
        float s[8] = {};
        #pragma unroll
        for (int h = 0; h < 8; ++h) {
            u16x8 pv = __builtin_nontemporal_load((const u16x8*)(p + ((size_t)h * N_TF + t) * N_GENE + g8));
            float r = rinv[h];
            #pragma unroll
            for (int j = 0; j < 8; ++j) s[j] += bf2f(pv[j]) * r;
        }
        f32x4 o0, o1;
        o0[0] = s[0]; o0[1] = s[1]; o0[2] = s[2]; o0[3] = s[3];
        o1[0] = s[4]; o1[1] = s[5]; o1[2] = s[6]; o1[3] = s[7];
        __builtin_nontemporal_store(o0, (f32x4*)(A_mean + (size_t)t * N_GENE + g8));
        __builtin_nontemporal_store(o1, (f32x4*)(A_mean + (size_t)t * N_GENE + g8 + 4));
    }
}

// ---------------------------------------------------------------- H_TF + H_G passthrough in one launch
__global__ __launch_bounds__(256) void copy_all(const int4* __restrict__ a, const int4* __restrict__ b,
                                                int4* __restrict__ da, int4* __restrict__ db) {
    const int bx = blockIdx.x;
    if (bx < 256) {
        int i = bx * 256 + threadIdx.x;            // 65536 int4 = 1 MB H_TF
        da[i] = a[i];
    } else {
        int i = (bx - 256) * 256 + threadIdx.x;    // 2097152 int4 = 32 MB H_G
        db[i] = b[i];
    }
}

// ---------------------------------------------------------------- launch
extern "C" void kernel_launch(void* const* d_in, const int* in_sizes, int n_in,
                              void* d_out, int out_size, void* d_ws, size_t ws_size,
                              hipStream_t stream) {
    const float* H_TF  = (const float*)d_in[0];
    const float* H_G   = (const float*)d_in[1];
    // evidence order: e0=bind(seq), e1=coexpr(exp), e2=know(txt)
    const float* z[3]  = { (const float*)d_in[3], (const float*)d_in[2], (const float*)d_in[4] };
    const int* tf_idx  = (const int*)d_in[5];
    const float* Wq[3] = { (const float*)d_in[6], (const float*)d_in[8], (const float*)d_in[10] };
    const float* Wk[3] = { (const float*)d_in[7], (const float*)d_in[9], (const float*)d_in[11] };
    const float* gw    = (const float*)d_in[12];
    const float* gb    = (const float*)d_in[13];
    float* out = (float*)d_out;

    // d_out layout (fp32): H_TF | H_G | A_mean | u_mean | alpha_mean
    float* out_HTF   = out;
    float* out_HG    = out + 262144;
    float* out_Amean = out + 262144 + 8388608;
    float* out_umean = out + 262144 + 8388608 + 8388608;
    float* out_alpha = out + 262144 + 8388608 + 8388608 + 8388608;

    // ws layout (bf16 intermediates)
    unsigned short* Wt = (unsigned short*)d_ws;        // 6 * 262144  (slot e*2 = Wq_e^T, e*2+1 = Wk_e^T)
    unsigned short* Kp = Wt + 6 * 262144;              // 3 * 16384*512
    unsigned short* Qp = Kp + 3 * (size_t)N_GENE * 512;// 3 * 512*512
    unsigned short* Pp = Qp + 3 * 512 * 512;           // 8 * 512 * 16384
    float*          Lp = (float*)(Pp + (size_t)8 * N_TF * N_GENE);  // 8*512 floats
    // Zb (bf16 copies of z) aliases Pp: Zb is dead before score_pass writes Pp
    unsigned short* Zb = Pp;                           // 3 * 16384*512 <= Pp size

    // 1) all preprocessing in one dispatch
    prep<<<13825, 256, 0, stream>>>(z[0], z[1], z[2], Zb,
                                    Wq[0], Wk[0], Wq[1], Wk[1], Wq[2], Wk[2], Wt, Lp);

    // 2) all 6 projection GEMMs in one dispatch
    gemm_all<<<dim3(4, 132, 3), 256, 0, stream>>>(Zb, Wt, Kp, Qp, tf_idx);

    // 3) fused score+gate+softmax
    score_pass<<<2048, 256, 0, stream>>>(Qp, Kp, gw, gb, Pp, Lp, out_umean, out_alpha);

    // 4) A_mean normalize+mean
    finalize_A<<<dim3(512, 4), 256, 0, stream>>>(Pp, Lp, out_Amean);

    // 5) passthrough copies
    copy_all<<<256 + 8192, 256, 0, stream>>>((const int4*)H_TF, (const int4*)H_G,
                                             (int4*)out_HTF, (int4*)out_HG);
}